// Round 1
// baseline (299.955 us; speedup 1.0000x reference)
//
#include <hip/hip_runtime.h>

#define NB 10

__device__ __forceinline__ void proc(float x, int lab, float* csum, int* pl) {
    float e = __expf(-x);
    float conf = 1.0f / (1.0f + e);
    int b = (int)ceilf(conf * 10.0f) - 1;
    b = min(max(b, 0), NB - 1);
    int packed = 1 | (lab << 16);
#pragma unroll
    for (int i = 0; i < NB; ++i) {
        bool m = (b == i);
        csum[i] += m ? conf : 0.0f;
        pl[i]   += m ? packed : 0;
    }
}

__global__ __launch_bounds__(256) void ece_partial(const float* __restrict__ logits,
                                                   const int* __restrict__ labels,
                                                   float* __restrict__ ws,
                                                   int n, int wstride) {
    float csum[NB];
    int pl[NB];
#pragma unroll
    for (int i = 0; i < NB; ++i) { csum[i] = 0.0f; pl[i] = 0; }

    const int n4 = n >> 2;
    const float4* __restrict__ l4 = (const float4*)logits;
    const int4*   __restrict__ b4 = (const int4*)labels;

    int tid = blockIdx.x * blockDim.x + threadIdx.x;
    int stride = gridDim.x * blockDim.x;
    for (int v = tid; v < n4; v += stride) {
        float4 x = l4[v];
        int4  lb = b4[v];
        proc(x.x, lb.x, csum, pl);
        proc(x.y, lb.y, csum, pl);
        proc(x.z, lb.z, csum, pl);
        proc(x.w, lb.w, csum, pl);
    }
    // scalar tail (n not divisible by 4) — handled by one thread
    if (tid == 0) {
        for (int j = n4 * 4; j < n; ++j) proc(logits[j], labels[j], csum, pl);
    }

    __shared__ float lds[3 * NB];
    if (threadIdx.x < 3 * NB) lds[threadIdx.x] = 0.0f;
    __syncthreads();

    int lane = threadIdx.x & 63;
#pragma unroll
    for (int i = 0; i < NB; ++i) {
        float c = csum[i];
        int p = pl[i];
#pragma unroll
        for (int off = 32; off > 0; off >>= 1) {
            c += __shfl_down(c, off, 64);
            p += __shfl_down(p, off, 64);
        }
        if (lane == 0) {
            atomicAdd(&lds[0 * NB + i], (float)(p & 0xffff));
            atomicAdd(&lds[1 * NB + i], (float)(p >> 16));
            atomicAdd(&lds[2 * NB + i], c);
        }
    }
    __syncthreads();
    if (threadIdx.x < 3 * NB) {
        atomicAdd(&ws[threadIdx.x * wstride], lds[threadIdx.x]);
    }
}

__global__ void ece_final(const float* __restrict__ ws, float* __restrict__ out, int wstride) {
    if (threadIdx.x == 0 && blockIdx.x == 0) {
        float ece = 0.0f, mx = 0.0f;
        for (int b = 0; b < NB; ++b) {
            float cnt = ws[(0 * NB + b) * wstride];
            float ls  = ws[(1 * NB + b) * wstride];
            float cs  = ws[(2 * NB + b) * wstride];
            float pos = 0.0f, cfb = 0.0f, e = 0.0f;
            if (cnt > 0.0f) {
                pos = ls / cnt;
                cfb = cs / cnt;
                e = fabsf(pos - cfb);
            }
            out[b] = pos;
            out[NB + b] = cfb;
            ece += e;
            mx = fmaxf(mx, e);
        }
        out[2 * NB] = ece;
        out[2 * NB + 1] = mx;
    }
}

extern "C" void kernel_launch(void* const* d_in, const int* in_sizes, int n_in,
                              void* d_out, int out_size, void* d_ws, size_t ws_size,
                              hipStream_t stream) {
    const float* logits = (const float*)d_in[0];
    const int*   labels = (const int*)d_in[1];
    float* out = (float*)d_out;
    float* ws  = (float*)d_ws;
    int n = in_sizes[0];

    // Pad each of the 30 accumulators to its own 64B line if workspace permits
    // (avoids same-L2-channel atomic serialization across blocks).
    int wstride = (ws_size >= 30 * 16 * sizeof(float)) ? 16 : 1;

    hipMemsetAsync(d_ws, 0, (size_t)(30 * wstride) * sizeof(float), stream);

    const int block = 256;
    const int grid = 1024;  // 262144 threads, 128 elems/thread, 32 float4 iters
    ece_partial<<<grid, block, 0, stream>>>(logits, labels, ws, n, wstride);
    ece_final<<<1, 64, 0, stream>>>(ws, out, wstride);
}